// Round 3
// baseline (362.597 us; speedup 1.0000x reference)
//
#include <hip/hip_runtime.h>

#define NB 32
#define NT 2048
#define ND 512
#define NH 64
#define NS 3
#define NBLKS 2
#define ROWLEN (2*ND + 1)   // 1025 floats per output row

typedef __attribute__((ext_vector_type(8))) short bf16x8;   // 8 bf16 = 4 VGPR
typedef float f32x4 __attribute__((ext_vector_type(4)));

// bf16 packed-weight workspace layout (ushort elements)
#define W1_OFF 0
#define W2_OFF 24576
#define WF_OFF 49152
#define WS_ELEMS 52224      // = 104448 bytes

__device__ __forceinline__ unsigned int f2bf(float f) {      // RNE f32->bf16
    unsigned int u = __float_as_uint(f);
    return (u + 0x7FFFu + ((u >> 16) & 1u)) >> 16;
}
__device__ __forceinline__ unsigned int pack2(float a, float b) {
    return f2bf(a) | (f2bf(b) << 16);
}

// Wave-level LDS ordering: DS ops from one wave execute in order on the LDS
// pipe, so cross-LANE (same-wave) RAW through a wave-private tile needs only a
// compiler fence, not s_barrier (which would force vmcnt(0) and drain the
// feature stores). Zero hardware cost.
__device__ __forceinline__ void wave_sync() {
    __builtin_amdgcn_fence(__ATOMIC_ACQ_REL, "wavefront");
    __builtin_amdgcn_wave_barrier();
    __builtin_amdgcn_fence(__ATOMIC_ACQ_REL, "wavefront");
}

__device__ __forceinline__ float bcast(float v, int l) {     // v_readlane (scalar pipe)
    return __int_as_float(__builtin_amdgcn_readlane(__float_as_int(v), l));
}

// One-shot f32 -> bf16 weight conversion into d_ws (runs every launch; d_ws is
// re-poisoned before each timed call).
__global__ __launch_bounds__(256) void prepack(
    const float* __restrict__ W1, const float* __restrict__ W2,
    const float* __restrict__ Wf, unsigned short* __restrict__ ws)
{
    int idx = blockIdx.x * 256 + threadIdx.x;
    if (idx < 24576) {
        ws[W1_OFF + idx] = (unsigned short)f2bf(W1[idx]);
    } else if (idx < 49152) {
        int o = idx - 24576;
        ws[W2_OFF + o] = (unsigned short)f2bf(W2[o]);
    } else if (idx < WS_ELEMS) {
        int o = idx - 49152;                 // [3][16][64], rows>=2 zero-padded
        int s = o >> 10, row = (o >> 6) & 15, m = o & 63;
        float v = (row < 2) ? Wf[s * 128 + row * 64 + m] : 0.0f;
        ws[WF_OFF + o] = (unsigned short)f2bf(v);
    }
}

// Block = 256 threads = 4 waves; each wave owns 16 rows end-to-end.
// Phase 1 (flow): all global LOADS live here; MFMA matvecs with wave-private
//   LDS tiles, wave_sync only -> no s_barrier anywhere in the kernel.
// Phase 2 (features): 256 coalesced dword stores per thread, issued after the
//   last load -> no vmcnt wait ever drains them; they retire at HBM rate while
//   the next resident block round computes its flow.
__global__ __launch_bounds__(256, 2) void nf_main(
    const float* __restrict__ trend, const float* __restrict__ seasonal,
    const float* __restrict__ residual,
    const float* __restrict__ Wt, const float* __restrict__ bt,
    const float* __restrict__ Ws, const float* __restrict__ bs,
    const float* __restrict__ b_init, const float* __restrict__ Wc0,
    const float* __restrict__ bc0,
    const float* __restrict__ b1, const float* __restrict__ b2,
    const float* __restrict__ Wcb, const float* __restrict__ bcb,
    const float* __restrict__ bf_, const unsigned short* __restrict__ wpk,
    float* __restrict__ out)
{
    __shared__ unsigned short s_X[4][16][72];   // per-wave act tile, stride 72 bf16

    const int tid  = threadIdx.x;
    const int row0 = blockIdx.x * 64;
    const int lane = tid & 63;
    const int wv_  = tid >> 6;
    const int r    = lane & 15;      // sample within wave tile; A-frag row; D col
    const int q    = lane >> 4;      // k-quad
    const int n    = row0 + wv_ * 16 + r;

    const float x   = residual[n];
    const float c   = ((n & (NT - 1)) == 0) ? 0.0f : residual[n - 1];
    const float trv = trend[n];
    const float sev = seasonal[n];

    unsigned short (* const X)[72] = s_X[wv_];
    const int u0 = 4 * q;            // this lane owns units 16t+u0+e

    float z = x, logdet = 0.0f;

    // ---------------- phase 1: flow (loads + MFMA, wave-synchronous) ----------------
    for (int i = 0; i < NS; ++i) {
        float h[4][4];
        #pragma unroll
        for (int t = 0; t < 4; ++t) {
            const int ub = i * NH + 16 * t + u0;
            const f32x4 wc  = *(const f32x4*)(Wc0 + ub);
            const f32x4 b0v = *(const f32x4*)(bc0 + ub);
            const f32x4 biv = *(const f32x4*)(b_init + ub);
            #pragma unroll
            for (int e = 0; e < 4; ++e) h[t][e] = fmaf(c, wc[e], b0v[e] + biv[e]);
        }

        for (int j = 0; j < NBLKS; ++j) {
            const int ij = i * NBLKS + j;
            #pragma unroll
            for (int t = 0; t < 4; ++t) {
                uint2 p;
                p.x = pack2(fmaxf(h[t][0], 0.f), fmaxf(h[t][1], 0.f));
                p.y = pack2(fmaxf(h[t][2], 0.f), fmaxf(h[t][3], 0.f));
                *(uint2*)&X[r][16 * t + u0] = p;
            }
            wave_sync();   // cross-lane RAW within this wave (DS pipe is in-order)

            f32x4 D[4];
            {   // t1 = relu(h) @ W1^T
                const unsigned short* Wb = wpk + W1_OFF + ij * 4096;
                bf16x8 bA = *(const bf16x8*)&X[r][8 * q];
                bf16x8 bB = *(const bf16x8*)&X[r][32 + 8 * q];
                #pragma unroll
                for (int t = 0; t < 4; ++t) {
                    bf16x8 a0 = *(const bf16x8*)&Wb[(16 * t + r) * 64 + 8 * q];
                    bf16x8 a1 = *(const bf16x8*)&Wb[(16 * t + r) * 64 + 32 + 8 * q];
                    f32x4 d = {0.f, 0.f, 0.f, 0.f};
                    d = __builtin_amdgcn_mfma_f32_16x16x32_bf16(a0, bA, d, 0, 0, 0);
                    d = __builtin_amdgcn_mfma_f32_16x16x32_bf16(a1, bB, d, 0, 0, 0);
                    D[t] = d;
                }
            }
            wave_sync();   // reads done before overwrite
            #pragma unroll
            for (int t = 0; t < 4; ++t) {
                const f32x4 bb = *(const f32x4*)(b1 + ij * NH + 16 * t + u0);
                uint2 p;
                p.x = pack2(fmaxf(D[t][0] + bb[0], 0.f), fmaxf(D[t][1] + bb[1], 0.f));
                p.y = pack2(fmaxf(D[t][2] + bb[2], 0.f), fmaxf(D[t][3] + bb[3], 0.f));
                *(uint2*)&X[r][16 * t + u0] = p;
            }
            wave_sync();

            {   // t2 = t1 @ W2^T
                const unsigned short* Wb = wpk + W2_OFF + ij * 4096;
                bf16x8 bA = *(const bf16x8*)&X[r][8 * q];
                bf16x8 bB = *(const bf16x8*)&X[r][32 + 8 * q];
                #pragma unroll
                for (int t = 0; t < 4; ++t) {
                    bf16x8 a0 = *(const bf16x8*)&Wb[(16 * t + r) * 64 + 8 * q];
                    bf16x8 a1 = *(const bf16x8*)&Wb[(16 * t + r) * 64 + 32 + 8 * q];
                    f32x4 d = {0.f, 0.f, 0.f, 0.f};
                    d = __builtin_amdgcn_mfma_f32_16x16x32_bf16(a0, bA, d, 0, 0, 0);
                    d = __builtin_amdgcn_mfma_f32_16x16x32_bf16(a1, bB, d, 0, 0, 0);
                    D[t] = d;
                }
            }
            // h += (t2 + b2) * sigmoid(c*Wcb + bcb)
            #pragma unroll
            for (int t = 0; t < 4; ++t) {
                const int ub = ij * NH + 16 * t + u0;
                const f32x4 b2v = *(const f32x4*)(b2 + ub);
                const f32x4 wg  = *(const f32x4*)(Wcb + ub);
                const f32x4 bg  = *(const f32x4*)(bcb + ub);
                #pragma unroll
                for (int e = 0; e < 4; ++e) {
                    float g  = fmaf(c, wg[e], bg[e]);
                    float sg = 1.0f / (1.0f + __expf(-g));
                    h[t][e] += (D[t][e] + b2v[e]) * sg;
                }
            }
            wave_sync();
        }

        // final Linear(H,2) via padded Wf: rows 0/1 of D = (o0,o1) on q==0 lanes
        #pragma unroll
        for (int t = 0; t < 4; ++t) {
            uint2 p;
            p.x = pack2(fmaxf(h[t][0], 0.f), fmaxf(h[t][1], 0.f));
            p.y = pack2(fmaxf(h[t][2], 0.f), fmaxf(h[t][3], 0.f));
            *(uint2*)&X[r][16 * t + u0] = p;
        }
        wave_sync();
        {
            const unsigned short* Wb = wpk + WF_OFF + i * 1024;
            bf16x8 bA = *(const bf16x8*)&X[r][8 * q];
            bf16x8 bB = *(const bf16x8*)&X[r][32 + 8 * q];
            bf16x8 a0 = *(const bf16x8*)&Wb[r * 64 + 8 * q];
            bf16x8 a1 = *(const bf16x8*)&Wb[r * 64 + 32 + 8 * q];
            f32x4 d = {0.f, 0.f, 0.f, 0.f};
            d = __builtin_amdgcn_mfma_f32_16x16x32_bf16(a0, bA, d, 0, 0, 0);
            d = __builtin_amdgcn_mfma_f32_16x16x32_bf16(a1, bB, d, 0, 0, 0);
            float o0 = d[0] + bf_[2 * i];
            float o1 = d[1] + bf_[2 * i + 1];
            float sp = log1pf(__expf(o0)) + 1e-3f;   // softplus + 1e-3
            z = fmaf(sp, z, o1);
            logdet += __logf(sp);
        }
        wave_sync();   // final reads done before next step's writes
    }

    if (q == 0)
        out[(size_t)n * ROWLEN + 2 * ND] = fmaf(-0.5f, z * z, logdet) - 0.91893853320467274178f;

    // ---------------- phase 2: feature stores (no loads after this point) ----------------
    float wv[16], bv[16];
    #pragma unroll
    for (int j = 0; j < 16; ++j) {
        const int cc = lane + 64 * j;
        wv[j] = (j < 8) ? Wt[cc] : Ws[cc - ND];
        bv[j] = (j < 8) ? bt[cc] : bs[cc - ND];
    }
    const int rbase = row0 + wv_ * 16;
    #pragma unroll
    for (int j = 0; j < 16; ++j) {
        const int cc = lane + 64 * j;
        const float src = (j < 8) ? trv : sev;
        #pragma unroll
        for (int rr = 0; rr < 16; ++rr) {
            out[(size_t)(rbase + rr) * ROWLEN + cc] = fmaf(bcast(src, rr), wv[j], bv[j]);
        }
    }
}

extern "C" void kernel_launch(void* const* d_in, const int* in_sizes, int n_in,
                              void* d_out, int out_size, void* d_ws, size_t ws_size,
                              hipStream_t stream) {
    const float* trend    = (const float*)d_in[0];
    const float* seasonal = (const float*)d_in[1];
    const float* residual = (const float*)d_in[2];
    const float* Wt       = (const float*)d_in[3];
    const float* bt       = (const float*)d_in[4];
    const float* Ws       = (const float*)d_in[5];
    const float* bs       = (const float*)d_in[6];
    const float* b_init   = (const float*)d_in[7];
    const float* Wc0      = (const float*)d_in[8];
    const float* bc0      = (const float*)d_in[9];
    const float* W1       = (const float*)d_in[10];
    const float* b1       = (const float*)d_in[11];
    const float* W2       = (const float*)d_in[12];
    const float* b2       = (const float*)d_in[13];
    const float* Wcb      = (const float*)d_in[14];
    const float* bcb      = (const float*)d_in[15];
    const float* Wf       = (const float*)d_in[16];
    const float* bfin     = (const float*)d_in[17];
    float* out            = (float*)d_out;
    unsigned short* wpk   = (unsigned short*)d_ws;

    hipLaunchKernelGGL(prepack, dim3((WS_ELEMS + 255) / 256), dim3(256), 0, stream,
                       W1, W2, Wf, wpk);

    const int nrows = NB * NT;                    // 65536
    hipLaunchKernelGGL(nf_main, dim3(nrows / 64), dim3(256), 0, stream,
                       trend, seasonal, residual, Wt, bt, Ws, bs,
                       b_init, Wc0, bc0, b1, b2, Wcb, bcb, bfin, wpk, out);
}